// Round 1
// baseline (1033.806 us; speedup 1.0000x reference)
//
#include <hip/hip_runtime.h>

#define NFEAT 512
#define NHID  128
#define NCLS  16
#define BETA  0.7f
#define OMB   (1.0f - BETA)
#define KIT   10   // k (HITS iterations) — harness always passes 10 (host cannot read device scalar during capture)

typedef float  f32x4  __attribute__((ext_vector_type(4)));
typedef __bf16 bf16x8 __attribute__((ext_vector_type(8)));

__device__ __forceinline__ unsigned short f2bf(float f) {
  unsigned u = __builtin_bit_cast(unsigned, f);
  u += 0x7fffu + ((u >> 16) & 1u);   // RNE
  return (unsigned short)(u >> 16);
}

// ---------------- CSR/CSC build ----------------
__global__ __launch_bounds__(256) void k_hist(const int* __restrict__ er, const int* __restrict__ ec,
                                              int* __restrict__ cr, int* __restrict__ cc, int E) {
  int i = blockIdx.x * 256 + threadIdx.x;
  if (i < E) { atomicAdd(&cr[er[i]], 1); atomicAdd(&cc[ec[i]], 1); }
}

__global__ __launch_bounds__(256) void k_scan_block(const int* __restrict__ in, int* __restrict__ outp,
                                                    int* __restrict__ bsum, int n) {
  __shared__ int s[256];
  int i = blockIdx.x * 256 + threadIdx.x;
  int v = (i < n) ? in[i] : 0;
  int acc = v;
  s[threadIdx.x] = acc;
  __syncthreads();
  for (int off = 1; off < 256; off <<= 1) {
    int t = (threadIdx.x >= off) ? s[threadIdx.x - off] : 0;
    __syncthreads();
    acc += t;
    s[threadIdx.x] = acc;
    __syncthreads();
  }
  if (i < n) outp[i] = acc - v;                 // exclusive within block
  if (threadIdx.x == 255) bsum[blockIdx.x] = acc;
}

__global__ __launch_bounds__(512) void k_scan_mid(int* __restrict__ bsum, int nb) {
  __shared__ int s[512];
  int v = (threadIdx.x < nb) ? bsum[threadIdx.x] : 0;
  int acc = v;
  s[threadIdx.x] = acc;
  __syncthreads();
  for (int off = 1; off < 512; off <<= 1) {
    int t = (threadIdx.x >= off) ? s[threadIdx.x - off] : 0;
    __syncthreads();
    acc += t;
    s[threadIdx.x] = acc;
    __syncthreads();
  }
  if (threadIdx.x < nb) bsum[threadIdx.x] = acc - v;  // exclusive
}

__global__ __launch_bounds__(256) void k_scan_add(int* __restrict__ outp, const int* __restrict__ bsum,
                                                  int n, int total) {
  int i = blockIdx.x * 256 + threadIdx.x;
  if (i < n) outp[i] += bsum[i >> 8];
  else if (i == n) outp[i] = total;
}

__global__ __launch_bounds__(256) void k_scatter(const int* __restrict__ er, const int* __restrict__ ec,
    const float* __restrict__ ev, int* __restrict__ curR, int* __restrict__ curC,
    int* __restrict__ csrC, float* __restrict__ csrV,
    int* __restrict__ cscR, float* __restrict__ cscV, int E) {
  int i = blockIdx.x * 256 + threadIdx.x;
  if (i >= E) return;
  int r = er[i], c = ec[i];
  float v = ev[i];
  int pr = atomicAdd(&curR[r], 1);
  csrC[pr] = c; csrV[pr] = v;
  int pc = atomicAdd(&curC[c], 1);
  cscR[pc] = r; cscV[pc] = v;
}

// ---------------- W1 transpose + bf16 convert: w1t[c][k] = bf16(W1[k][c]) ----------------
__global__ __launch_bounds__(256) void k_w1t(const float* __restrict__ W1, unsigned short* __restrict__ w1t) {
  int i = blockIdx.x * 256 + threadIdx.x;
  if (i >= NFEAT * NHID) return;
  int k = i / NHID, c = i % NHID;
  w1t[c * NFEAT + k] = f2bf(W1[i]);
}

// ---------------- GEMM1: xw = x @ W1 (bf16 MFMA, f32 accum/out) ----------------
// block = 256 thr (4 waves, 2x2), tile 128(M) x 128(N), K-step 32
__global__ __launch_bounds__(256) void k_gemm1(const float* __restrict__ x,
    const unsigned short* __restrict__ w1t, float* __restrict__ xw, int M) {
  __shared__ unsigned short As[128][40];   // pad 32->40 (80B row stride) to spread banks
  __shared__ unsigned short Bs[128][40];
  int tid = threadIdx.x;
  int lane = tid & 63, wid = tid >> 6;
  int wr = wid >> 1, wc = wid & 1;
  int row0 = blockIdx.x * 128;
  f32x4 acc[4][4];
#pragma unroll
  for (int m = 0; m < 4; ++m)
#pragma unroll
    for (int n = 0; n < 4; ++n) acc[m][n] = (f32x4)(0.f);

  int sr  = tid >> 1;            // 0..127
  int skh = (tid & 1) << 4;      // 0 or 16 (k within 32-step)

  for (int k0 = 0; k0 < NFEAT; k0 += 32) {
    // stage A: 128 rows x 32 k, f32 -> bf16
    float4 f0 = {0,0,0,0}, f1 = {0,0,0,0}, f2 = {0,0,0,0}, f3 = {0,0,0,0};
    int grow = row0 + sr;
    if (grow < M) {
      const float4* s4 = (const float4*)(x + (size_t)grow * NFEAT + k0 + skh);
      f0 = s4[0]; f1 = s4[1]; f2 = s4[2]; f3 = s4[3];
    }
    unsigned p0 = f2bf(f0.x) | ((unsigned)f2bf(f0.y) << 16);
    unsigned p1 = f2bf(f0.z) | ((unsigned)f2bf(f0.w) << 16);
    unsigned p2 = f2bf(f1.x) | ((unsigned)f2bf(f1.y) << 16);
    unsigned p3 = f2bf(f1.z) | ((unsigned)f2bf(f1.w) << 16);
    unsigned p4 = f2bf(f2.x) | ((unsigned)f2bf(f2.y) << 16);
    unsigned p5 = f2bf(f2.z) | ((unsigned)f2bf(f2.w) << 16);
    unsigned p6 = f2bf(f3.x) | ((unsigned)f2bf(f3.y) << 16);
    unsigned p7 = f2bf(f3.z) | ((unsigned)f2bf(f3.w) << 16);
    uint4 wA0 = {p0, p1, p2, p3}, wA1 = {p4, p5, p6, p7};
    *(uint4*)&As[sr][skh]     = wA0;
    *(uint4*)&As[sr][skh + 8] = wA1;
    // stage B: 128 cols x 32 k (already bf16, k-major)
    const uint4* bsrc = (const uint4*)(w1t + sr * NFEAT + k0 + skh);
    *(uint4*)&Bs[sr][skh]     = bsrc[0];
    *(uint4*)&Bs[sr][skh + 8] = bsrc[1];
    __syncthreads();

    int fr = lane & 15, fc = lane >> 4;   // fr = row/col in frag, fc = k-chunk (8 contiguous)
    bf16x8 bfrag[4];
#pragma unroll
    for (int n = 0; n < 4; ++n)
      bfrag[n] = *(const bf16x8*)&Bs[wc * 64 + n * 16 + fr][fc * 8];
#pragma unroll
    for (int m = 0; m < 4; ++m) {
      bf16x8 afrag = *(const bf16x8*)&As[wr * 64 + m * 16 + fr][fc * 8];
#pragma unroll
      for (int n = 0; n < 4; ++n)
        acc[m][n] = __builtin_amdgcn_mfma_f32_16x16x32_bf16(afrag, bfrag[n], acc[m][n], 0, 0, 0);
    }
    __syncthreads();
  }
  int orow = lane >> 4, ocol = lane & 15;   // C/D: col=lane&15, row=(lane>>4)*4+i  [m89]
#pragma unroll
  for (int m = 0; m < 4; ++m)
#pragma unroll
    for (int i = 0; i < 4; ++i) {
      int row = row0 + wr * 64 + m * 16 + orow * 4 + i;
      if (row < M) {
#pragma unroll
        for (int n = 0; n < 4; ++n)
          xw[(size_t)row * NHID + wc * 64 + n * 16 + ocol] = acc[m][n][i];
      }
    }
}

// ---------------- fused spmm1: hw[r] = (relu(adj@xw + b1)[r]) @ W2  ----------------
// one wave per row (4 rows/block); 2 feats per lane
__global__ __launch_bounds__(256) void k_spmm1(const float* __restrict__ xw,
    const int* __restrict__ rp, const int* __restrict__ ci, const float* __restrict__ cv,
    const float* __restrict__ b1, const float* __restrict__ W2,
    float* __restrict__ hw, int N) {
  __shared__ float sW2[NHID * NCLS];
  __shared__ float sb1[NHID];
  for (int i = threadIdx.x; i < NHID * NCLS; i += 256) sW2[i] = W2[i];
  if (threadIdx.x < NHID) sb1[threadIdx.x] = b1[threadIdx.x];
  __syncthreads();
  int lane = threadIdx.x & 63;
  int r = blockIdx.x * 4 + (threadIdx.x >> 6);
  if (r >= N) return;
  int beg = rp[r], end = rp[r + 1];
  float ax = 0.f, ay = 0.f;
  const float* base = xw + 2 * lane;
  int e = beg;
  for (; e + 4 <= end; e += 4) {
    int   c0 = ci[e], c1 = ci[e + 1], c2 = ci[e + 2], c3 = ci[e + 3];
    float v0 = cv[e], v1 = cv[e + 1], v2 = cv[e + 2], v3 = cv[e + 3];
    float2 g0 = *(const float2*)(base + (size_t)c0 * NHID);
    float2 g1 = *(const float2*)(base + (size_t)c1 * NHID);
    float2 g2 = *(const float2*)(base + (size_t)c2 * NHID);
    float2 g3 = *(const float2*)(base + (size_t)c3 * NHID);
    ax += v0 * g0.x + v1 * g1.x + v2 * g2.x + v3 * g3.x;
    ay += v0 * g0.y + v1 * g1.y + v2 * g2.y + v3 * g3.y;
  }
  for (; e < end; ++e) {
    int c = ci[e]; float v = cv[e];
    float2 g = *(const float2*)(base + (size_t)c * NHID);
    ax += v * g.x; ay += v * g.y;
  }
  float h0 = fmaxf(ax + sb1[2 * lane], 0.f);
  float h1 = fmaxf(ay + sb1[2 * lane + 1], 0.f);
  float pj[NCLS];
#pragma unroll
  for (int j = 0; j < NCLS; ++j)
    pj[j] = h0 * sW2[(2 * lane) * NCLS + j] + h1 * sW2[(2 * lane + 1) * NCLS + j];
#pragma unroll
  for (int off = 32; off >= 1; off >>= 1)
#pragma unroll
    for (int j = 0; j < NCLS; ++j)
      pj[j] += __shfl_xor(pj[j], off, 64);
  if (lane == 0) {
    float4* o = (float4*)(hw + (size_t)r * NCLS);
    o[0] = make_float4(pj[0],  pj[1],  pj[2],  pj[3]);
    o[1] = make_float4(pj[4],  pj[5],  pj[6],  pj[7]);
    o[2] = make_float4(pj[8],  pj[9],  pj[10], pj[11]);
    o[3] = make_float4(pj[12], pj[13], pj[14], pj[15]);
  }
}

// ---------------- spmm2: h = adj @ hw + b2 ----------------
// 16 lanes per row, 16 rows per block
__global__ __launch_bounds__(256) void k_spmm2(const float* __restrict__ hw,
    const int* __restrict__ rp, const int* __restrict__ ci, const float* __restrict__ cv,
    const float* __restrict__ b2, float* __restrict__ h, int N) {
  int j = threadIdx.x & 15;
  int r = blockIdx.x * 16 + (threadIdx.x >> 4);
  if (r >= N) return;
  int beg = rp[r], end = rp[r + 1];
  float acc = 0.f;
  int e = beg;
  for (; e + 4 <= end; e += 4) {
    int   c0 = ci[e], c1 = ci[e + 1], c2 = ci[e + 2], c3 = ci[e + 3];
    float v0 = cv[e], v1 = cv[e + 1], v2 = cv[e + 2], v3 = cv[e + 3];
    acc += v0 * hw[(size_t)c0 * NCLS + j] + v1 * hw[(size_t)c1 * NCLS + j]
         + v2 * hw[(size_t)c2 * NCLS + j] + v3 * hw[(size_t)c3 * NCLS + j];
  }
  for (; e < end; ++e) acc += cv[e] * hw[(size_t)ci[e] * NCLS + j];
  h[(size_t)r * NCLS + j] = acc + b2[j];
}

// ---------------- init auth/hub ----------------
__global__ __launch_bounds__(256) void k_fill1(float* __restrict__ a, float* __restrict__ b, int N) {
  int i = blockIdx.x * 256 + threadIdx.x;
  if (i < N) { a[i] = 1.f; b[i] = 1.f; }
}

// ---------------- dual spmv (two independent matvecs in one launch) ----------------
__global__ __launch_bounds__(256) void k_spmv2(
    const int* __restrict__ pA, const int* __restrict__ iA, const float* __restrict__ vA,
    const float* __restrict__ sA, float* __restrict__ dA,
    const int* __restrict__ pB, const int* __restrict__ iB, const float* __restrict__ vB,
    const float* __restrict__ sB, float* __restrict__ dB, int N, int halfBlocks) {
  bool second = blockIdx.x >= halfBlocks;
  int b = second ? blockIdx.x - halfBlocks : blockIdx.x;
  const int*   rp = second ? pB : pA;
  const int*   ix = second ? iB : iA;
  const float* vl = second ? vB : vA;
  const float* sv = second ? sB : sA;
  float*       dv = second ? dB : dA;
  int g = threadIdx.x >> 4, j = threadIdx.x & 15;
  int r = b * 16 + g;
  if (r >= N) return;
  int beg = rp[r], end = rp[r + 1];
  float acc = 0.f;
  for (int e = beg + j; e < end; e += 16)
    acc += vl[e] * sv[ix[e]];
#pragma unroll
  for (int off = 8; off >= 1; off >>= 1) acc += __shfl_xor(acc, off, 64);
  if (j == 0) dv[r] = acc;
}

// ---------------- reductions for softmax over z = auth+hub ----------------
__global__ __launch_bounds__(256) void k_redmax(const float* __restrict__ a, const float* __restrict__ b,
                                                float* __restrict__ part, int n) {
  float m = -3.0e38f;
  for (int i = blockIdx.x * 256 + threadIdx.x; i < n; i += gridDim.x * 256)
    m = fmaxf(m, a[i] + b[i]);
#pragma unroll
  for (int off = 32; off >= 1; off >>= 1) m = fmaxf(m, __shfl_xor(m, off, 64));
  __shared__ float lm[4];
  if ((threadIdx.x & 63) == 0) lm[threadIdx.x >> 6] = m;
  __syncthreads();
  if (threadIdx.x == 0)
    part[blockIdx.x] = fmaxf(fmaxf(lm[0], lm[1]), fmaxf(lm[2], lm[3]));
}

__global__ __launch_bounds__(512) void k_redmax2(const float* __restrict__ part, float* __restrict__ scal, int n) {
  float m = (threadIdx.x < n) ? part[threadIdx.x] : -3.0e38f;
#pragma unroll
  for (int off = 32; off >= 1; off >>= 1) m = fmaxf(m, __shfl_xor(m, off, 64));
  __shared__ float lm[8];
  if ((threadIdx.x & 63) == 0) lm[threadIdx.x >> 6] = m;
  __syncthreads();
  if (threadIdx.x == 0) {
    float mm = lm[0];
#pragma unroll
    for (int i = 1; i < 8; ++i) mm = fmaxf(mm, lm[i]);
    scal[0] = mm;
  }
}

__global__ __launch_bounds__(256) void k_redsum(const float* __restrict__ a, const float* __restrict__ b,
                                                const float* __restrict__ scal, float* __restrict__ part, int n) {
  float M = scal[0];
  float s = 0.f;
  for (int i = blockIdx.x * 256 + threadIdx.x; i < n; i += gridDim.x * 256)
    s += expf(a[i] + b[i] - M);
#pragma unroll
  for (int off = 32; off >= 1; off >>= 1) s += __shfl_xor(s, off, 64);
  __shared__ float lm[4];
  if ((threadIdx.x & 63) == 0) lm[threadIdx.x >> 6] = s;
  __syncthreads();
  if (threadIdx.x == 0) part[blockIdx.x] = lm[0] + lm[1] + lm[2] + lm[3];
}

__global__ __launch_bounds__(512) void k_redsum2(const float* __restrict__ part, float* __restrict__ scal, int n) {
  float s = (threadIdx.x < n) ? part[threadIdx.x] : 0.f;
#pragma unroll
  for (int off = 32; off >= 1; off >>= 1) s += __shfl_xor(s, off, 64);
  __shared__ float lm[8];
  if ((threadIdx.x & 63) == 0) lm[threadIdx.x >> 6] = s;
  __syncthreads();
  if (threadIdx.x == 0) {
    float ss = 0.f;
#pragma unroll
    for (int i = 0; i < 8; ++i) ss += lm[i];
    scal[1] = ss;
  }
}

// ---------------- q[j] = sum_i exp(z_i - M) * p[i][j]  (unnormalized) ----------------
__global__ __launch_bounds__(256) void k_q(const float* __restrict__ a, const float* __restrict__ b,
    const float* __restrict__ scal, const float* __restrict__ p, float* __restrict__ qun, int n) {
  float M = scal[0];
  int g = threadIdx.x >> 4, j = threadIdx.x & 15;
  float acc = 0.f;
  for (int i = blockIdx.x * 16 + g; i < n; i += gridDim.x * 16) {
    float w = expf(a[i] + b[i] - M);
    acc += w * p[(size_t)i * NCLS + j];
  }
  __shared__ float ls[16][16];
  ls[g][j] = acc;
  __syncthreads();
  if (threadIdx.x < 16) {
    float s = 0.f;
#pragma unroll
    for (int gg = 0; gg < 16; ++gg) s += ls[gg][threadIdx.x];
    atomicAdd(&qun[threadIdx.x], s);
  }
}

// ---------------- final: propagation recurrence + log_softmax ----------------
// out_t = ((1-B)*hits)@out_{t-1} + B*p collapses to out = sig + B*p with
// sig_1 = (1-B)*q, sig_t = (1-B)*sig_{t-1} + (1-B)*B*q   (Sum(hits)=1 by construction)
__global__ __launch_bounds__(256) void k_final(const float* __restrict__ p,
    const float* __restrict__ qun, const float* __restrict__ scal,
    const int* __restrict__ lptr, float* __restrict__ out, int n) {
  float Z = scal[1];
  int L = lptr[0];
  float qn[NCLS], sig[NCLS];
#pragma unroll
  for (int j = 0; j < NCLS; ++j) qn[j] = qun[j] / Z;
#pragma unroll
  for (int j = 0; j < NCLS; ++j) sig[j] = OMB * qn[j];
  for (int t = 1; t < L; ++t)
#pragma unroll
    for (int j = 0; j < NCLS; ++j) sig[j] = OMB * sig[j] + OMB * BETA * qn[j];
  for (int i = blockIdx.x * 256 + threadIdx.x; i < n; i += gridDim.x * 256) {
    const float4* pr = (const float4*)(p + (size_t)i * NCLS);
    float4 r0 = pr[0], r1 = pr[1], r2 = pr[2], r3 = pr[3];
    float lg[NCLS];
    lg[0]  = sig[0]  + BETA * r0.x; lg[1]  = sig[1]  + BETA * r0.y;
    lg[2]  = sig[2]  + BETA * r0.z; lg[3]  = sig[3]  + BETA * r0.w;
    lg[4]  = sig[4]  + BETA * r1.x; lg[5]  = sig[5]  + BETA * r1.y;
    lg[6]  = sig[6]  + BETA * r1.z; lg[7]  = sig[7]  + BETA * r1.w;
    lg[8]  = sig[8]  + BETA * r2.x; lg[9]  = sig[9]  + BETA * r2.y;
    lg[10] = sig[10] + BETA * r2.z; lg[11] = sig[11] + BETA * r2.w;
    lg[12] = sig[12] + BETA * r3.x; lg[13] = sig[13] + BETA * r3.y;
    lg[14] = sig[14] + BETA * r3.z; lg[15] = sig[15] + BETA * r3.w;
    float m = lg[0];
#pragma unroll
    for (int j = 1; j < NCLS; ++j) m = fmaxf(m, lg[j]);
    float s = 0.f;
#pragma unroll
    for (int j = 0; j < NCLS; ++j) s += expf(lg[j] - m);
    float lse = m + logf(s);
    float4* o = (float4*)(out + (size_t)i * NCLS);
    o[0] = make_float4(lg[0]  - lse, lg[1]  - lse, lg[2]  - lse, lg[3]  - lse);
    o[1] = make_float4(lg[4]  - lse, lg[5]  - lse, lg[6]  - lse, lg[7]  - lse);
    o[2] = make_float4(lg[8]  - lse, lg[9]  - lse, lg[10] - lse, lg[11] - lse);
    o[3] = make_float4(lg[12] - lse, lg[13] - lse, lg[14] - lse, lg[15] - lse);
  }
}

extern "C" void kernel_launch(void* const* d_in, const int* in_sizes, int n_in,
                              void* d_out, int out_size, void* d_ws, size_t ws_size,
                              hipStream_t stream) {
  const float* x  = (const float*)d_in[0];
  const int*   er = (const int*)d_in[1];
  const int*   ec = (const int*)d_in[2];
  const float* ev = (const float*)d_in[3];
  const float* W1 = (const float*)d_in[4];
  const float* b1 = (const float*)d_in[5];
  const float* W2 = (const float*)d_in[6];
  const float* b2 = (const float*)d_in[7];
  const int* lptr = (const int*)d_in[9];
  int N = in_sizes[0] / NFEAT;
  int E = in_sizes[1];
  float* out = (float*)d_out;

  char* w = (char*)d_ws;
  size_t off = 0;
  auto alloc = [&](size_t bytes) { char* p = w + off; off += (bytes + 255) & ~(size_t)255; return p; };
  float*          xw    = (float*)alloc((size_t)N * NHID * 4);
  float*          hw    = (float*)alloc((size_t)N * NCLS * 4);
  float*          h     = (float*)alloc((size_t)N * NCLS * 4);
  int*            csrP  = (int*)alloc((size_t)(N + 1) * 4);
  int*            csrC  = (int*)alloc((size_t)E * 4);
  float*          csrV  = (float*)alloc((size_t)E * 4);
  int*            cscP  = (int*)alloc((size_t)(N + 1) * 4);
  int*            cscR  = (int*)alloc((size_t)E * 4);
  float*          cscV  = (float*)alloc((size_t)E * 4);
  int*            cntR  = (int*)alloc((size_t)N * 4);
  int*            cntC  = (int*)alloc((size_t)N * 4);
  float*          auth  = (float*)alloc((size_t)N * 4);
  float*          hub   = (float*)alloc((size_t)N * 4);
  float*          authT = (float*)alloc((size_t)N * 4);
  float*          hubT  = (float*)alloc((size_t)N * 4);
  int*            bsum  = (int*)alloc(512 * 4);
  float*          part  = (float*)alloc(512 * 4);
  float*          qun   = (float*)alloc(16 * 4);
  float*          scal  = (float*)alloc(2 * 4);
  unsigned short* w1t   = (unsigned short*)alloc((size_t)NFEAT * NHID * 2);
  if (off > ws_size) return;  // workspace insufficient — bail (signals via wrong output)

  hipMemsetAsync(cntR, 0, (size_t)N * 4, stream);
  hipMemsetAsync(cntC, 0, (size_t)N * 4, stream);
  hipMemsetAsync(qun, 0, 16 * 4, stream);

  int gE = (E + 255) / 256;
  int nb = (N + 255) / 256;
  k_hist<<<gE, 256, 0, stream>>>(er, ec, cntR, cntC, E);
  k_scan_block<<<nb, 256, 0, stream>>>(cntR, csrP, bsum, N);
  k_scan_mid<<<1, 512, 0, stream>>>(bsum, nb);
  k_scan_add<<<nb, 256, 0, stream>>>(csrP, bsum, N, E);
  k_scan_block<<<nb, 256, 0, stream>>>(cntC, cscP, bsum, N);
  k_scan_mid<<<1, 512, 0, stream>>>(bsum, nb);
  k_scan_add<<<nb, 256, 0, stream>>>(cscP, bsum, N, E);
  hipMemcpyAsync(cntR, csrP, (size_t)N * 4, hipMemcpyDeviceToDevice, stream);
  hipMemcpyAsync(cntC, cscP, (size_t)N * 4, hipMemcpyDeviceToDevice, stream);
  k_scatter<<<gE, 256, 0, stream>>>(er, ec, ev, cntR, cntC, csrC, csrV, cscR, cscV, E);

  k_w1t<<<(NFEAT * NHID + 255) / 256, 256, 0, stream>>>(W1, w1t);
  k_gemm1<<<(N + 127) / 128, 256, 0, stream>>>(x, w1t, xw, N);
  k_spmm1<<<(N + 3) / 4, 256, 0, stream>>>(xw, csrP, csrC, csrV, b1, W2, hw, N);
  k_spmm2<<<(N + 15) / 16, 256, 0, stream>>>(hw, csrP, csrC, csrV, b2, h, N);

  k_fill1<<<nb, 256, 0, stream>>>(auth, hub, N);
  int gs = (N + 15) / 16;
  for (int it = 0; it < KIT; ++it) {
    // auth1 = A@auth, hub1 = A.T@hub
    k_spmv2<<<2 * gs, 256, 0, stream>>>(csrP, csrC, csrV, auth, authT,
                                        cscP, cscR, cscV, hub, hubT, N, gs);
    // auth = A.T@auth1, hub = A@hub1
    k_spmv2<<<2 * gs, 256, 0, stream>>>(cscP, cscR, cscV, authT, auth,
                                        csrP, csrC, csrV, hubT, hub, N, gs);
  }

  k_redmax<<<392, 256, 0, stream>>>(auth, hub, part, N);
  k_redmax2<<<1, 512, 0, stream>>>(part, scal, 392);
  k_redsum<<<392, 256, 0, stream>>>(auth, hub, scal, part, N);
  k_redsum2<<<1, 512, 0, stream>>>(part, scal, 392);
  k_q<<<256, 256, 0, stream>>>(auth, hub, scal, h, qun, N);
  k_final<<<392, 256, 0, stream>>>(h, qun, scal, lptr, out, N);
}